// Round 16
// baseline (182.197 us; speedup 1.0000x reference)
//
#include <hip/hip_runtime.h>

static constexpr int N_NODES = 50000;
static constexpr int N_EDGES = 1600000;
static constexpr int CIN = 32;
static constexpr int HID = 64;
static constexpr int NBUCK = (N_NODES + 31) / 32; // 1563 buckets of 32 nodes
static constexpr int NB_BLD = 128;                // build blocks
static constexpr int EPB2 = N_EDGES / NB_BLD;     // 12500 edges per build block
static constexpr int NTB2 = (N_NODES + 63) / 64;  // 782 transform blocks (64 nodes)

__device__ __forceinline__ unsigned short f2bf(float f) {
    unsigned int u = __float_as_uint(f);
    u = (u + 0x7fffu + ((u >> 16) & 1u)) >> 16;   // RNE
    return (unsigned short)u;
}
__device__ __forceinline__ float bfhi(unsigned int u) { return __uint_as_float(u & 0xffff0000u); }
__device__ __forceinline__ float bflo(unsigned int u) { return __uint_as_float(u << 16); }

// ---------------- build: LDS-cursor bucket sort + within-bucket node sort ----

__global__ void __launch_bounds__(256)
histB_kernel(const int* __restrict__ ei, int* __restrict__ part) {
    __shared__ int hist[NBUCK];
    for (int i = threadIdx.x; i < NBUCK; i += 256) hist[i] = 0;
    __syncthreads();
    const int base = blockIdx.x * EPB2;
    const int t = threadIdx.x;
    for (int i0 = 0; i0 < EPB2; i0 += 1024) {
        int d[4];
#pragma unroll
        for (int k = 0; k < 4; ++k) {
            const int i = i0 + k * 256 + t;
            d[k] = (i < EPB2) ? ei[N_EDGES + base + i] : -1;
        }
#pragma unroll
        for (int k = 0; k < 4; ++k)
            if (d[k] >= 0) atomicAdd(&hist[d[k] >> 5], 1);
    }
    __syncthreads();
    for (int i = threadIdx.x; i < NBUCK; i += 256)
        part[i * NB_BLD + blockIdx.x] = hist[i];
}

__global__ void __launch_bounds__(NB_BLD)
scanA_kernel(int* __restrict__ part, int* __restrict__ btot) {
    __shared__ int s[NB_BLD];
    const int t = threadIdx.x;
    const int v = part[blockIdx.x * NB_BLD + t];
    s[t] = v;
    __syncthreads();
    for (int st = 1; st < NB_BLD; st <<= 1) {
        int u = (t >= st) ? s[t - st] : 0;
        __syncthreads();
        s[t] += u;
        __syncthreads();
    }
    part[blockIdx.x * NB_BLD + t] = s[t] - v;
    if (t == NB_BLD - 1) btot[blockIdx.x] = s[NB_BLD - 1];
}

__global__ void __launch_bounds__(1024)
scanB_kernel(const int* __restrict__ btot, int* __restrict__ bstart) {
    __shared__ int pairs[1024];
    __shared__ int v0s[1024];
    const int t = threadIdx.x;
    const int i0 = 2 * t, i1 = 2 * t + 1;
    const int v0 = (i0 < NBUCK) ? btot[i0] : 0;
    const int v1 = (i1 < NBUCK) ? btot[i1] : 0;
    v0s[t] = v0;
    const int p = v0 + v1;
    pairs[t] = p;
    __syncthreads();
    for (int st = 1; st < 1024; st <<= 1) {
        int u = (t >= st) ? pairs[t - st] : 0;
        __syncthreads();
        pairs[t] += u;
        __syncthreads();
    }
    const int base = pairs[t] - p;
    if (i0 < NBUCK) bstart[i0] = base;
    if (i1 < NBUCK) bstart[i1] = base + v0s[t];
    if (t == 1023) bstart[NBUCK] = pairs[1023];   // == N_EDGES
}

__global__ void __launch_bounds__(256)
scatterB_kernel(const int* __restrict__ ei, const int* __restrict__ part,
                const int* __restrict__ bstart, unsigned* __restrict__ bentry) {
    __shared__ int cur[NBUCK];
    for (int i = threadIdx.x; i < NBUCK; i += 256)
        cur[i] = bstart[i] + part[i * NB_BLD + blockIdx.x];
    __syncthreads();
    const int base = blockIdx.x * EPB2;
    const int t = threadIdx.x;
    for (int i0 = 0; i0 < EPB2; i0 += 1024) {
        int s[4], d[4];
#pragma unroll
        for (int k = 0; k < 4; ++k) {
            const int i = i0 + k * 256 + t;
            const bool val = i < EPB2;
            s[k] = val ? ei[base + i] : 0;
            d[k] = val ? ei[N_EDGES + base + i] : -1;
        }
#pragma unroll
        for (int k = 0; k < 4; ++k)
            if (d[k] >= 0) {
                const int pos = atomicAdd(&cur[d[k] >> 5], 1);
                bentry[pos] = ((unsigned)s[k] << 5) | (unsigned)(d[k] & 31);
            }
    }
}

__global__ void __launch_bounds__(256)
sortW_kernel(const unsigned* __restrict__ bentry, const int* __restrict__ bstart,
             int* __restrict__ sorted_src, int* __restrict__ off) {
    __shared__ int cnt[32];
    __shared__ int base[33];
    __shared__ int cur[32];
    const int b = blockIdx.x, t = threadIdx.x;
    const int s0 = bstart[b], s1 = bstart[b + 1];
    if (t < 32) cnt[t] = 0;
    __syncthreads();
    for (int i = s0 + t; i < s1; i += 256)
        atomicAdd(&cnt[bentry[i] & 31], 1);
    __syncthreads();
    if (t == 0) {
        int run = s0;
#pragma unroll
        for (int l = 0; l < 32; ++l) { base[l] = run; cur[l] = run; run += cnt[l]; }
        base[32] = run;
    }
    __syncthreads();
    if (t <= 32) {
        const int gn = b * 32 + t;
        if (gn <= N_NODES) off[gn] = base[t];
    }
    for (int i = s0 + t; i < s1; i += 256) {
        const unsigned e = bentry[i];
        const int pos = atomicAdd(&cur[e & 31], 1);
        sorted_src[pos] = (int)(e >> 5);
    }
}

// ---------------- agg0 (R9-proven): mean of neighbor x rows -> mean0b ------
__global__ void __launch_bounds__(256)
agg0_kernel(const float* __restrict__ x,
            const int* __restrict__ off, const int* __restrict__ src,
            unsigned short* __restrict__ mean0b) {
    const int node = blockIdx.x * 4 + (threadIdx.x >> 6);
    const int lane = threadIdx.x & 63;
    if (node >= N_NODES) return;
    const int e0 = off[node], e1 = off[node + 1];
    const int deg = e1 - e0;
    const int grp = lane >> 3, cg = lane & 7;

    float a[4] = {0, 0, 0, 0};
    for (int base = e0; base < e1; base += 64) {
        const int cnt = min(64, e1 - base);
        const int p = base + lane;
        const int sidx = (p < e1) ? src[p] : 0;
        const int nb = (cnt + 7) >> 3;
        float4 u[8];
#pragma unroll
        for (int t = 0; t < 8; ++t) u[t] = make_float4(0.f, 0.f, 0.f, 0.f);
#pragma unroll
        for (int t = 0; t < 8; ++t) {
            if (t < nb) {
                const int pos = (t << 3) | grp;
                const int s = __shfl(sidx, pos);
                if (pos < cnt)
                    u[t] = *reinterpret_cast<const float4*>(x + (size_t)s * CIN + cg * 4);
            }
        }
#pragma unroll
        for (int t = 0; t < 8; ++t) {
            a[0] += u[t].x; a[1] += u[t].y; a[2] += u[t].z; a[3] += u[t].w;
        }
    }
#pragma unroll
    for (int j = 0; j < 4; ++j) {
        a[j] += __shfl_xor(a[j], 8);
        a[j] += __shfl_xor(a[j], 16);
        a[j] += __shfl_xor(a[j], 32);
    }
    const float inv = 1.0f / fmaxf((float)deg, 1.0f);
    if (grp == 0) {
        uint2 o;
        o.x = (unsigned)f2bf(a[0] * inv) | ((unsigned)f2bf(a[1] * inv) << 16);
        o.y = (unsigned)f2bf(a[2] * inv) | ((unsigned)f2bf(a[3] * inv) << 16);
        reinterpret_cast<uint2*>(mean0b)[node * 8 + cg] = o;
    }
}

// ---------------- agg1 (R9-proven): mean of neighbor hb rows -> mean1f ------
__global__ void __launch_bounds__(256)
agg1_kernel(const unsigned short* __restrict__ hb,
            const int* __restrict__ off, const int* __restrict__ src,
            float* __restrict__ mean1f) {
    const int node = blockIdx.x * 4 + (threadIdx.x >> 6);
    const int lane = threadIdx.x & 63;
    if (node >= N_NODES) return;
    const int e0 = off[node], e1 = off[node + 1];
    const int deg = e1 - e0;
    const int grp = lane >> 3, cg = lane & 7;

    float a[8] = {0, 0, 0, 0, 0, 0, 0, 0};
    for (int base = e0; base < e1; base += 64) {
        const int cnt = min(64, e1 - base);
        const int p = base + lane;
        const int sidx = (p < e1) ? src[p] : 0;
        const int nb = (cnt + 7) >> 3;
        uint4 u[8];
#pragma unroll
        for (int t = 0; t < 8; ++t) u[t] = make_uint4(0u, 0u, 0u, 0u);
#pragma unroll
        for (int t = 0; t < 8; ++t) {
            if (t < nb) {
                const int pos = (t << 3) | grp;
                const int s = __shfl(sidx, pos);
                if (pos < cnt)
                    u[t] = *reinterpret_cast<const uint4*>(hb + (size_t)s * HID + cg * 8);
            }
        }
#pragma unroll
        for (int t = 0; t < 8; ++t) {
            a[0] += bflo(u[t].x); a[1] += bfhi(u[t].x);
            a[2] += bflo(u[t].y); a[3] += bfhi(u[t].y);
            a[4] += bflo(u[t].z); a[5] += bfhi(u[t].z);
            a[6] += bflo(u[t].w); a[7] += bfhi(u[t].w);
        }
    }
#pragma unroll
    for (int j = 0; j < 8; ++j) {
        a[j] += __shfl_xor(a[j], 8);
        a[j] += __shfl_xor(a[j], 16);
        a[j] += __shfl_xor(a[j], 32);
    }
    const float inv = 1.0f / fmaxf((float)deg, 1.0f);
    if (grp == 0) {
        float4 o1 = make_float4(a[0] * inv, a[1] * inv, a[2] * inv, a[3] * inv);
        float4 o2 = make_float4(a[4] * inv, a[5] * inv, a[6] * inv, a[7] * inv);
        float4* dst = reinterpret_cast<float4*>(mean1f + (size_t)node * HID + cg * 8);
        dst[0] = o1; dst[1] = o2;
    }
}

// ---------------- transform 0: wave = 16 nodes; weights direct from L2 -----
__global__ void __launch_bounds__(256)
transform0_kernel(const float* __restrict__ x,
                  const unsigned short* __restrict__ mean0b,
                  const float* __restrict__ Wl0, const float* __restrict__ Wr0,
                  const float* __restrict__ b0,
                  unsigned short* __restrict__ hb) {
    const int t = threadIdx.x;
    const int lane = t & 63, wid = t >> 6;
    const int cg = lane & 15, rep = lane >> 4;
    const int nbase = blockIdx.x * 64 + wid * 16 + rep;    // + 4*s
    const float4 bv = reinterpret_cast<const float4*>(b0)[cg];
    float acc[4][4];
#pragma unroll
    for (int s = 0; s < 4; ++s) {
        acc[s][0] = bv.x; acc[s][1] = bv.y; acc[s][2] = bv.z; acc[s][3] = bv.w;
    }
    for (int kc = 0; kc < CIN; kc += 4) {
        float4 wl4[4], wr4[4];
#pragma unroll
        for (int kk = 0; kk < 4; ++kk) {
            wl4[kk] = *reinterpret_cast<const float4*>(Wl0 + (kc + kk) * HID + 4 * cg);
            wr4[kk] = *reinterpret_cast<const float4*>(Wr0 + (kc + kk) * HID + 4 * cg);
        }
#pragma unroll
        for (int s = 0; s < 4; ++s) {
            const int n = nbase + 4 * s;
            if (n < N_NODES) {
                const uint2 mu = *reinterpret_cast<const uint2*>(mean0b + (size_t)n * CIN + kc);
                const float4 xv = *reinterpret_cast<const float4*>(x + (size_t)n * CIN + kc);
                const float m4[4] = {bflo(mu.x), bfhi(mu.x), bflo(mu.y), bfhi(mu.y)};
                const float x4[4] = {xv.x, xv.y, xv.z, xv.w};
#pragma unroll
                for (int kk = 0; kk < 4; ++kk) {
                    acc[s][0] = fmaf(m4[kk], wl4[kk].x, fmaf(x4[kk], wr4[kk].x, acc[s][0]));
                    acc[s][1] = fmaf(m4[kk], wl4[kk].y, fmaf(x4[kk], wr4[kk].y, acc[s][1]));
                    acc[s][2] = fmaf(m4[kk], wl4[kk].z, fmaf(x4[kk], wr4[kk].z, acc[s][2]));
                    acc[s][3] = fmaf(m4[kk], wl4[kk].w, fmaf(x4[kk], wr4[kk].w, acc[s][3]));
                }
            }
        }
    }
#pragma unroll
    for (int s = 0; s < 4; ++s) {
        float ss = acc[s][0] * acc[s][0] + acc[s][1] * acc[s][1] +
                   acc[s][2] * acc[s][2] + acc[s][3] * acc[s][3];
        ss += __shfl_xor(ss, 1);
        ss += __shfl_xor(ss, 2);
        ss += __shfl_xor(ss, 4);
        ss += __shfl_xor(ss, 8);   // reduce over 16-lane group (same node)
        const float sc = 1.0f / fmaxf(sqrtf(ss), 1e-12f);
        const int n = nbase + 4 * s;
        if (n < N_NODES) {
            uint2 o;
            o.x = (unsigned)f2bf(fmaxf(acc[s][0] * sc, 0.f)) |
                  ((unsigned)f2bf(fmaxf(acc[s][1] * sc, 0.f)) << 16);
            o.y = (unsigned)f2bf(fmaxf(acc[s][2] * sc, 0.f)) |
                  ((unsigned)f2bf(fmaxf(acc[s][3] * sc, 0.f)) << 16);
            *reinterpret_cast<uint2*>(hb + (size_t)n * HID + cg * 4) = o;
        }
    }
}

// ---------------- transform 1: wave = 16 nodes; weights from L2; + cls -----
static constexpr int SVP = 68;   // padded sV row stride (floats)
__global__ void __launch_bounds__(256)
transform1_kernel(const unsigned short* __restrict__ hb,
                  const float* __restrict__ mean1f,
                  const float* __restrict__ Wl1, const float* __restrict__ Wr1,
                  const float* __restrict__ b1,
                  const float* __restrict__ Wc1, const float* __restrict__ bc1,
                  const float* __restrict__ Wc2, const float* __restrict__ bc2,
                  float* __restrict__ out) {
    __shared__ float sV[64 * SVP];     // 17KB only
    const int t = threadIdx.x;
    const int lane = t & 63, wid = t >> 6;
    const int cg = lane & 15, rep = lane >> 4;
    const int nbase = blockIdx.x * 64 + wid * 16 + rep;    // + 4*s
    const float4 bv = reinterpret_cast<const float4*>(b1)[cg];
    float acc[4][4];
#pragma unroll
    for (int s = 0; s < 4; ++s) {
        acc[s][0] = bv.x; acc[s][1] = bv.y; acc[s][2] = bv.z; acc[s][3] = bv.w;
    }
    for (int kc = 0; kc < HID; kc += 4) {
        float4 wl4[4], wr4[4];
#pragma unroll
        for (int kk = 0; kk < 4; ++kk) {
            wl4[kk] = *reinterpret_cast<const float4*>(Wl1 + (kc + kk) * HID + 4 * cg);
            wr4[kk] = *reinterpret_cast<const float4*>(Wr1 + (kc + kk) * HID + 4 * cg);
        }
#pragma unroll
        for (int s = 0; s < 4; ++s) {
            const int n = nbase + 4 * s;
            if (n < N_NODES) {
                const float4 mv = *reinterpret_cast<const float4*>(mean1f + (size_t)n * HID + kc);
                const uint2 hu = *reinterpret_cast<const uint2*>(hb + (size_t)n * HID + kc);
                const float m4[4] = {mv.x, mv.y, mv.z, mv.w};
                const float h4[4] = {bflo(hu.x), bfhi(hu.x), bflo(hu.y), bfhi(hu.y)};
#pragma unroll
                for (int kk = 0; kk < 4; ++kk) {
                    acc[s][0] = fmaf(m4[kk], wl4[kk].x, fmaf(h4[kk], wr4[kk].x, acc[s][0]));
                    acc[s][1] = fmaf(m4[kk], wl4[kk].y, fmaf(h4[kk], wr4[kk].y, acc[s][1]));
                    acc[s][2] = fmaf(m4[kk], wl4[kk].z, fmaf(h4[kk], wr4[kk].z, acc[s][2]));
                    acc[s][3] = fmaf(m4[kk], wl4[kk].w, fmaf(h4[kk], wr4[kk].w, acc[s][3]));
                }
            }
        }
    }
#pragma unroll
    for (int s = 0; s < 4; ++s) {
        float ss = acc[s][0] * acc[s][0] + acc[s][1] * acc[s][1] +
                   acc[s][2] * acc[s][2] + acc[s][3] * acc[s][3];
        ss += __shfl_xor(ss, 1);
        ss += __shfl_xor(ss, 2);
        ss += __shfl_xor(ss, 4);
        ss += __shfl_xor(ss, 8);
        const float sc = 1.0f / fmaxf(sqrtf(ss), 1e-12f);
        const int ln = wid * 16 + rep + 4 * s;    // local node 0..63
        sV[ln * SVP + 4 * cg + 0] = acc[s][0] * sc;
        sV[ln * SVP + 4 * cg + 1] = acc[s][1] * sc;
        sV[ln * SVP + 4 * cg + 2] = acc[s][2] * sc;
        sV[ln * SVP + 4 * cg + 3] = acc[s][3] * sc;
    }
    __syncthreads();

    // classifier: thread -> local node n2 = t>>2, hidden units ig*8..ig*8+7
    const int n2 = t >> 2, ig = t & 3;
    float c1[8];
#pragma unroll
    for (int u = 0; u < 8; ++u) c1[u] = bc1[ig * 8 + u];
#pragma unroll 4
    for (int c = 0; c < HID; ++c) {
        const float vv = sV[n2 * SVP + c];
        const float4 w0 = *reinterpret_cast<const float4*>(Wc1 + c * 32 + ig * 8);
        const float4 w1 = *reinterpret_cast<const float4*>(Wc1 + c * 32 + ig * 8 + 4);
        c1[0] = fmaf(vv, w0.x, c1[0]);
        c1[1] = fmaf(vv, w0.y, c1[1]);
        c1[2] = fmaf(vv, w0.z, c1[2]);
        c1[3] = fmaf(vv, w0.w, c1[3]);
        c1[4] = fmaf(vv, w1.x, c1[4]);
        c1[5] = fmaf(vv, w1.y, c1[5]);
        c1[6] = fmaf(vv, w1.z, c1[6]);
        c1[7] = fmaf(vv, w1.w, c1[7]);
    }
    float pp = 0.f;
#pragma unroll
    for (int u = 0; u < 8; ++u)
        pp = fmaf(fmaxf(c1[u], 0.f), Wc2[ig * 8 + u], pp);
    pp += __shfl_xor(pp, 1);
    pp += __shfl_xor(pp, 2);   // combine the 4 ig groups
    const int g = blockIdx.x * 64 + n2;
    if (ig == 0 && g < N_NODES) out[g] = pp + bc2[0];
}

extern "C" void kernel_launch(void* const* d_in, const int* in_sizes, int n_in,
                              void* d_out, int out_size, void* d_ws, size_t ws_size,
                              hipStream_t stream) {
    const float* x   = (const float*)d_in[0];
    const int*   ei  = (const int*)d_in[1];
    const float* Wl0 = (const float*)d_in[2];
    const float* b0  = (const float*)d_in[3];
    const float* Wr0 = (const float*)d_in[4];
    const float* Wl1 = (const float*)d_in[5];
    const float* b1  = (const float*)d_in[6];
    const float* Wr1 = (const float*)d_in[7];
    const float* Wc1 = (const float*)d_in[8];
    const float* bc1 = (const float*)d_in[9];
    const float* Wc2 = (const float*)d_in[10];
    const float* bc2 = (const float*)d_in[11];
    float* out = (float*)d_out;

    // ws layout (float offsets), liveness-packed (R9-proven):
    float* W = (float*)d_ws;
    int*            part   = (int*)W;                         // dead after scatterB
    int*            btot   = (int*)(W + 200064);
    int*            bstart = (int*)(W + 201632);
    unsigned*       bentry = (unsigned*)(W + 1600000);        // dead after sortW
    unsigned short* mean0b = (unsigned short*)W;              // dead after transform0
    float*          mean1f = W;                               // written by agg1
    int*            sorted_src = (int*)(W + 3200000);
    int*            off    = (int*)(W + 4800000);
    unsigned short* hb     = (unsigned short*)(W + 4850016);  // N*64 bf16

    const int T = 256;
    histB_kernel<<<NB_BLD, T, 0, stream>>>(ei, part);
    scanA_kernel<<<NBUCK, NB_BLD, 0, stream>>>(part, btot);
    scanB_kernel<<<1, 1024, 0, stream>>>(btot, bstart);
    scatterB_kernel<<<NB_BLD, T, 0, stream>>>(ei, part, bstart, bentry);
    sortW_kernel<<<NBUCK, T, 0, stream>>>(bentry, bstart, sorted_src, off);

    const int ngrid = (N_NODES + 3) / 4;
    agg0_kernel<<<ngrid, T, 0, stream>>>(x, off, sorted_src, mean0b);
    transform0_kernel<<<NTB2, T, 0, stream>>>(x, mean0b, Wl0, Wr0, b0, hb);
    agg1_kernel<<<ngrid, T, 0, stream>>>(hb, off, sorted_src, mean1f);
    transform1_kernel<<<NTB2, T, 0, stream>>>(hb, mean1f, Wl1, Wr1, b1,
                                              Wc1, bc1, Wc2, bc2, out);
}

// Round 17
// 160.706 us; speedup vs baseline: 1.1337x; 1.1337x over previous
//
#include <hip/hip_runtime.h>

static constexpr int N_NODES = 50000;
static constexpr int N_EDGES = 1600000;
static constexpr int CIN = 32;
static constexpr int HID = 64;
static constexpr int NBUCK = (N_NODES + 31) / 32; // 1563 buckets of 32 nodes
static constexpr int NB_BLD = 128;                // build blocks
static constexpr int EPB2 = N_EDGES / NB_BLD;     // 12500 edges per build block
static constexpr int NTB2 = (N_NODES + 63) / 64;  // 782 transform blocks (64 nodes)
static constexpr int SMAX = 3072;                 // per-bucket entry cap (mean 1024, sd 32)

__device__ __forceinline__ unsigned short f2bf(float f) {
    unsigned int u = __float_as_uint(f);
    u = (u + 0x7fffu + ((u >> 16) & 1u)) >> 16;   // RNE
    return (unsigned short)u;
}
__device__ __forceinline__ float bfhi(unsigned int u) { return __uint_as_float(u & 0xffff0000u); }
__device__ __forceinline__ float bflo(unsigned int u) { return __uint_as_float(u << 16); }

// ---------------- build: LDS-cursor bucket sort ----------------

__global__ void __launch_bounds__(256)
histB_kernel(const int* __restrict__ ei, int* __restrict__ part) {
    __shared__ int hist[NBUCK];
    for (int i = threadIdx.x; i < NBUCK; i += 256) hist[i] = 0;
    __syncthreads();
    const int base = blockIdx.x * EPB2;
    const int t = threadIdx.x;
    for (int i0 = 0; i0 < EPB2; i0 += 1024) {
        int d[4];
#pragma unroll
        for (int k = 0; k < 4; ++k) {
            const int i = i0 + k * 256 + t;
            d[k] = (i < EPB2) ? ei[N_EDGES + base + i] : -1;
        }
#pragma unroll
        for (int k = 0; k < 4; ++k)
            if (d[k] >= 0) atomicAdd(&hist[d[k] >> 5], 1);
    }
    __syncthreads();
    for (int i = threadIdx.x; i < NBUCK; i += 256)
        part[i * NB_BLD + blockIdx.x] = hist[i];
}

__global__ void __launch_bounds__(NB_BLD)
scanA_kernel(int* __restrict__ part, int* __restrict__ btot) {
    __shared__ int s[NB_BLD];
    const int t = threadIdx.x;
    const int v = part[blockIdx.x * NB_BLD + t];
    s[t] = v;
    __syncthreads();
    for (int st = 1; st < NB_BLD; st <<= 1) {
        int u = (t >= st) ? s[t - st] : 0;
        __syncthreads();
        s[t] += u;
        __syncthreads();
    }
    part[blockIdx.x * NB_BLD + t] = s[t] - v;
    if (t == NB_BLD - 1) btot[blockIdx.x] = s[NB_BLD - 1];
}

__global__ void __launch_bounds__(1024)
scanB_kernel(const int* __restrict__ btot, int* __restrict__ bstart) {
    __shared__ int pairs[1024];
    __shared__ int v0s[1024];
    const int t = threadIdx.x;
    const int i0 = 2 * t, i1 = 2 * t + 1;
    const int v0 = (i0 < NBUCK) ? btot[i0] : 0;
    const int v1 = (i1 < NBUCK) ? btot[i1] : 0;
    v0s[t] = v0;
    const int p = v0 + v1;
    pairs[t] = p;
    __syncthreads();
    for (int st = 1; st < 1024; st <<= 1) {
        int u = (t >= st) ? pairs[t - st] : 0;
        __syncthreads();
        pairs[t] += u;
        __syncthreads();
    }
    const int base = pairs[t] - p;
    if (i0 < NBUCK) bstart[i0] = base;
    if (i1 < NBUCK) bstart[i1] = base + v0s[t];
    if (t == 1023) bstart[NBUCK] = pairs[1023];   // == N_EDGES
}

__global__ void __launch_bounds__(256)
scatterB_kernel(const int* __restrict__ ei, const int* __restrict__ part,
                const int* __restrict__ bstart, unsigned* __restrict__ bentry) {
    __shared__ int cur[NBUCK];
    for (int i = threadIdx.x; i < NBUCK; i += 256)
        cur[i] = bstart[i] + part[i * NB_BLD + blockIdx.x];
    __syncthreads();
    const int base = blockIdx.x * EPB2;
    const int t = threadIdx.x;
    for (int i0 = 0; i0 < EPB2; i0 += 1024) {
        int s[4], d[4];
#pragma unroll
        for (int k = 0; k < 4; ++k) {
            const int i = i0 + k * 256 + t;
            const bool val = i < EPB2;
            s[k] = val ? ei[base + i] : 0;
            d[k] = val ? ei[N_EDGES + base + i] : -1;
        }
#pragma unroll
        for (int k = 0; k < 4; ++k)
            if (d[k] >= 0) {
                const int pos = atomicAdd(&cur[d[k] >> 5], 1);
                bentry[pos] = ((unsigned)s[k] << 5) | (unsigned)(d[k] & 31);
            }
    }
}

// ---------------- agg0s: fused within-bucket sort + x-row mean -------------
// block per bucket. Phase A: LDS-sort bucket entries to node order (emit
// off + sorted_src for agg1). Phase B: gather x rows, src from LDS.
__global__ void __launch_bounds__(256)
agg0s_kernel(const float* __restrict__ x,
             const unsigned* __restrict__ bentry, const int* __restrict__ bstart,
             int* __restrict__ sorted_src, int* __restrict__ off,
             unsigned short* __restrict__ mean0b) {
    __shared__ int cnt[32];
    __shared__ int base[33];   // 0-based entry offsets within bucket
    __shared__ int cur[32];
    __shared__ unsigned short sSrc[SMAX];   // 6KB (src < 50000 < 2^16)
    const int b = blockIdx.x, t = threadIdx.x;
    const int s0 = bstart[b], s1 = bstart[b + 1];
    const int m = s1 - s0;
    if (t < 32) cnt[t] = 0;
    __syncthreads();
    for (int i = t; i < m; i += 256)
        atomicAdd(&cnt[bentry[s0 + i] & 31], 1);
    __syncthreads();
    if (t == 0) {
        int run = 0;
#pragma unroll
        for (int l = 0; l < 32; ++l) { base[l] = run; cur[l] = run; run += cnt[l]; }
        base[32] = run;   // == m
    }
    __syncthreads();
    if (t <= 32) {
        const int gn = b * 32 + t;
        if (gn <= N_NODES) off[gn] = s0 + base[t];
    }
    for (int i = t; i < m; i += 256) {
        const unsigned e = bentry[s0 + i];
        const int pos = atomicAdd(&cur[e & 31], 1);
        const int srcv = (int)(e >> 5);
        if (pos < SMAX) sSrc[pos] = (unsigned short)srcv;
        sorted_src[s0 + pos] = srcv;
    }
    __syncthreads();

    // Phase B: 4 waves x 8 nodes; 8 edge-slots x 8 lanes per wave.
    const int lane = t & 63, wid = t >> 6;
    const int grp = lane >> 3, cg = lane & 7;
#pragma unroll
    for (int j = 0; j < 8; ++j) {
        const int l = wid * 8 + j;            // local node 0..31
        const int e0 = base[l], e1 = base[l + 1];
        const int deg = e1 - e0;
        float a[4] = {0, 0, 0, 0};
        for (int be = e0; be < e1; be += 64) {
            const int cnt_ = min(64, e1 - be);
            const int nb = (cnt_ + 7) >> 3;
            float4 u[8];
#pragma unroll
            for (int tt = 0; tt < 8; ++tt) u[tt] = make_float4(0.f, 0.f, 0.f, 0.f);
#pragma unroll
            for (int tt = 0; tt < 8; ++tt) {
                if (tt < nb) {
                    const int pos = be + ((tt << 3) | grp);
                    if (pos < e1) {
                        const int s = (int)sSrc[pos];   // LDS broadcast among 8 lanes
                        u[tt] = *reinterpret_cast<const float4*>(x + (size_t)s * CIN + cg * 4);
                    }
                }
            }
#pragma unroll
            for (int tt = 0; tt < 8; ++tt) {
                a[0] += u[tt].x; a[1] += u[tt].y; a[2] += u[tt].z; a[3] += u[tt].w;
            }
        }
#pragma unroll
        for (int jj = 0; jj < 4; ++jj) {
            a[jj] += __shfl_xor(a[jj], 8);
            a[jj] += __shfl_xor(a[jj], 16);
            a[jj] += __shfl_xor(a[jj], 32);
        }
        const float inv = 1.0f / fmaxf((float)deg, 1.0f);
        const int gn = b * 32 + l;
        if (grp == 0 && gn < N_NODES) {
            uint2 o;
            o.x = (unsigned)f2bf(a[0] * inv) | ((unsigned)f2bf(a[1] * inv) << 16);
            o.y = (unsigned)f2bf(a[2] * inv) | ((unsigned)f2bf(a[3] * inv) << 16);
            reinterpret_cast<uint2*>(mean0b)[gn * 8 + cg] = o;
        }
    }
}

// ---------------- agg1 (R9-proven): mean of neighbor hb rows -> mean1f ------
__global__ void __launch_bounds__(256)
agg1_kernel(const unsigned short* __restrict__ hb,
            const int* __restrict__ off, const int* __restrict__ src,
            float* __restrict__ mean1f) {
    const int node = blockIdx.x * 4 + (threadIdx.x >> 6);
    const int lane = threadIdx.x & 63;
    if (node >= N_NODES) return;
    const int e0 = off[node], e1 = off[node + 1];
    const int deg = e1 - e0;
    const int grp = lane >> 3, cg = lane & 7;

    float a[8] = {0, 0, 0, 0, 0, 0, 0, 0};
    for (int base = e0; base < e1; base += 64) {
        const int cnt = min(64, e1 - base);
        const int p = base + lane;
        const int sidx = (p < e1) ? src[p] : 0;
        const int nb = (cnt + 7) >> 3;
        uint4 u[8];
#pragma unroll
        for (int t = 0; t < 8; ++t) u[t] = make_uint4(0u, 0u, 0u, 0u);
#pragma unroll
        for (int t = 0; t < 8; ++t) {
            if (t < nb) {
                const int pos = (t << 3) | grp;
                const int s = __shfl(sidx, pos);
                if (pos < cnt)
                    u[t] = *reinterpret_cast<const uint4*>(hb + (size_t)s * HID + cg * 8);
            }
        }
#pragma unroll
        for (int t = 0; t < 8; ++t) {
            a[0] += bflo(u[t].x); a[1] += bfhi(u[t].x);
            a[2] += bflo(u[t].y); a[3] += bfhi(u[t].y);
            a[4] += bflo(u[t].z); a[5] += bfhi(u[t].z);
            a[6] += bflo(u[t].w); a[7] += bfhi(u[t].w);
        }
    }
#pragma unroll
    for (int j = 0; j < 8; ++j) {
        a[j] += __shfl_xor(a[j], 8);
        a[j] += __shfl_xor(a[j], 16);
        a[j] += __shfl_xor(a[j], 32);
    }
    const float inv = 1.0f / fmaxf((float)deg, 1.0f);
    if (grp == 0) {
        float4 o1 = make_float4(a[0] * inv, a[1] * inv, a[2] * inv, a[3] * inv);
        float4 o2 = make_float4(a[4] * inv, a[5] * inv, a[6] * inv, a[7] * inv);
        float4* dst = reinterpret_cast<float4*>(mean1f + (size_t)node * HID + cg * 8);
        dst[0] = o1; dst[1] = o2;
    }
}

// ---------------- transform 0 (R15-proven): wave = 16 nodes; LDS weights ---
__global__ void __launch_bounds__(256)
transform0_kernel(const float* __restrict__ x,
                  const unsigned short* __restrict__ mean0b,
                  const float* __restrict__ Wl0, const float* __restrict__ Wr0,
                  const float* __restrict__ b0,
                  unsigned short* __restrict__ hb) {
    __shared__ float sWl[CIN * HID];   // 8KB
    __shared__ float sWr[CIN * HID];   // 8KB
    const int t = threadIdx.x;
    reinterpret_cast<float4*>(sWl)[t]       = reinterpret_cast<const float4*>(Wl0)[t];
    reinterpret_cast<float4*>(sWl)[t + 256] = reinterpret_cast<const float4*>(Wl0)[t + 256];
    reinterpret_cast<float4*>(sWr)[t]       = reinterpret_cast<const float4*>(Wr0)[t];
    reinterpret_cast<float4*>(sWr)[t + 256] = reinterpret_cast<const float4*>(Wr0)[t + 256];
    __syncthreads();

    const int lane = t & 63, wid = t >> 6;
    const int cg = lane & 15, rep = lane >> 4;
    const int nbase = blockIdx.x * 64 + wid * 16 + rep;    // + 4*s
    const float4 bv = reinterpret_cast<const float4*>(b0)[cg];
    float acc[4][4];
#pragma unroll
    for (int s = 0; s < 4; ++s) {
        acc[s][0] = bv.x; acc[s][1] = bv.y; acc[s][2] = bv.z; acc[s][3] = bv.w;
    }
    for (int kc = 0; kc < CIN; kc += 4) {
        float4 wl4[4], wr4[4];
#pragma unroll
        for (int kk = 0; kk < 4; ++kk) {
            wl4[kk] = *reinterpret_cast<const float4*>(sWl + (kc + kk) * HID + 4 * cg);
            wr4[kk] = *reinterpret_cast<const float4*>(sWr + (kc + kk) * HID + 4 * cg);
        }
#pragma unroll
        for (int s = 0; s < 4; ++s) {
            const int n = nbase + 4 * s;
            if (n < N_NODES) {
                const uint2 mu = *reinterpret_cast<const uint2*>(mean0b + (size_t)n * CIN + kc);
                const float4 xv = *reinterpret_cast<const float4*>(x + (size_t)n * CIN + kc);
                const float m4[4] = {bflo(mu.x), bfhi(mu.x), bflo(mu.y), bfhi(mu.y)};
                const float x4[4] = {xv.x, xv.y, xv.z, xv.w};
#pragma unroll
                for (int kk = 0; kk < 4; ++kk) {
                    acc[s][0] = fmaf(m4[kk], wl4[kk].x, fmaf(x4[kk], wr4[kk].x, acc[s][0]));
                    acc[s][1] = fmaf(m4[kk], wl4[kk].y, fmaf(x4[kk], wr4[kk].y, acc[s][1]));
                    acc[s][2] = fmaf(m4[kk], wl4[kk].z, fmaf(x4[kk], wr4[kk].z, acc[s][2]));
                    acc[s][3] = fmaf(m4[kk], wl4[kk].w, fmaf(x4[kk], wr4[kk].w, acc[s][3]));
                }
            }
        }
    }
#pragma unroll
    for (int s = 0; s < 4; ++s) {
        float ss = acc[s][0] * acc[s][0] + acc[s][1] * acc[s][1] +
                   acc[s][2] * acc[s][2] + acc[s][3] * acc[s][3];
        ss += __shfl_xor(ss, 1);
        ss += __shfl_xor(ss, 2);
        ss += __shfl_xor(ss, 4);
        ss += __shfl_xor(ss, 8);   // reduce over 16-lane group (same node)
        const float sc = 1.0f / fmaxf(sqrtf(ss), 1e-12f);
        const int n = nbase + 4 * s;
        if (n < N_NODES) {
            uint2 o;
            o.x = (unsigned)f2bf(fmaxf(acc[s][0] * sc, 0.f)) |
                  ((unsigned)f2bf(fmaxf(acc[s][1] * sc, 0.f)) << 16);
            o.y = (unsigned)f2bf(fmaxf(acc[s][2] * sc, 0.f)) |
                  ((unsigned)f2bf(fmaxf(acc[s][3] * sc, 0.f)) << 16);
            *reinterpret_cast<uint2*>(hb + (size_t)n * HID + cg * 4) = o;
        }
    }
}

// ---------------- transform 1: LDS sWl/sWr + sV; Wc1 from L2 ----------------
static constexpr int SVP = 68;   // padded sV row stride (floats)
__global__ void __launch_bounds__(256)
transform1_kernel(const unsigned short* __restrict__ hb,
                  const float* __restrict__ mean1f,
                  const float* __restrict__ Wl1, const float* __restrict__ Wr1,
                  const float* __restrict__ b1,
                  const float* __restrict__ Wc1, const float* __restrict__ bc1,
                  const float* __restrict__ Wc2, const float* __restrict__ bc2,
                  float* __restrict__ out) {
    __shared__ float sWl[HID * HID];   // 16KB
    __shared__ float sWr[HID * HID];   // 16KB
    __shared__ float sV[64 * SVP];     // 17KB  (total ~49KB -> 3 blocks/CU)
    const int t = threadIdx.x;
#pragma unroll
    for (int i = 0; i < 4; ++i) {
        reinterpret_cast<float4*>(sWl)[t + 256 * i] = reinterpret_cast<const float4*>(Wl1)[t + 256 * i];
        reinterpret_cast<float4*>(sWr)[t + 256 * i] = reinterpret_cast<const float4*>(Wr1)[t + 256 * i];
    }
    __syncthreads();

    const int lane = t & 63, wid = t >> 6;
    const int cg = lane & 15, rep = lane >> 4;
    const int nbase = blockIdx.x * 64 + wid * 16 + rep;    // + 4*s
    const float4 bv = reinterpret_cast<const float4*>(b1)[cg];
    float acc[4][4];
#pragma unroll
    for (int s = 0; s < 4; ++s) {
        acc[s][0] = bv.x; acc[s][1] = bv.y; acc[s][2] = bv.z; acc[s][3] = bv.w;
    }
    for (int kc = 0; kc < HID; kc += 4) {
        float4 wl4[4], wr4[4];
#pragma unroll
        for (int kk = 0; kk < 4; ++kk) {
            wl4[kk] = *reinterpret_cast<const float4*>(sWl + (kc + kk) * HID + 4 * cg);
            wr4[kk] = *reinterpret_cast<const float4*>(sWr + (kc + kk) * HID + 4 * cg);
        }
#pragma unroll
        for (int s = 0; s < 4; ++s) {
            const int n = nbase + 4 * s;
            if (n < N_NODES) {
                const float4 mv = *reinterpret_cast<const float4*>(mean1f + (size_t)n * HID + kc);
                const uint2 hu = *reinterpret_cast<const uint2*>(hb + (size_t)n * HID + kc);
                const float m4[4] = {mv.x, mv.y, mv.z, mv.w};
                const float h4[4] = {bflo(hu.x), bfhi(hu.x), bflo(hu.y), bfhi(hu.y)};
#pragma unroll
                for (int kk = 0; kk < 4; ++kk) {
                    acc[s][0] = fmaf(m4[kk], wl4[kk].x, fmaf(h4[kk], wr4[kk].x, acc[s][0]));
                    acc[s][1] = fmaf(m4[kk], wl4[kk].y, fmaf(h4[kk], wr4[kk].y, acc[s][1]));
                    acc[s][2] = fmaf(m4[kk], wl4[kk].z, fmaf(h4[kk], wr4[kk].z, acc[s][2]));
                    acc[s][3] = fmaf(m4[kk], wl4[kk].w, fmaf(h4[kk], wr4[kk].w, acc[s][3]));
                }
            }
        }
    }
#pragma unroll
    for (int s = 0; s < 4; ++s) {
        float ss = acc[s][0] * acc[s][0] + acc[s][1] * acc[s][1] +
                   acc[s][2] * acc[s][2] + acc[s][3] * acc[s][3];
        ss += __shfl_xor(ss, 1);
        ss += __shfl_xor(ss, 2);
        ss += __shfl_xor(ss, 4);
        ss += __shfl_xor(ss, 8);
        const float sc = 1.0f / fmaxf(sqrtf(ss), 1e-12f);
        const int ln = wid * 16 + rep + 4 * s;    // local node 0..63
        sV[ln * SVP + 4 * cg + 0] = acc[s][0] * sc;
        sV[ln * SVP + 4 * cg + 1] = acc[s][1] * sc;
        sV[ln * SVP + 4 * cg + 2] = acc[s][2] * sc;
        sV[ln * SVP + 4 * cg + 3] = acc[s][3] * sc;
    }
    __syncthreads();

    // classifier: thread -> local node n2 = t>>2, hidden units ig*8..ig*8+7
    // Wc1 read from global (8KB, L2-resident across all blocks)
    const int n2 = t >> 2, ig = t & 3;
    float c1[8];
#pragma unroll
    for (int u = 0; u < 8; ++u) c1[u] = bc1[ig * 8 + u];
#pragma unroll 4
    for (int c = 0; c < HID; ++c) {
        const float vv = sV[n2 * SVP + c];
        const float4 w0 = *reinterpret_cast<const float4*>(Wc1 + c * 32 + ig * 8);
        const float4 w1 = *reinterpret_cast<const float4*>(Wc1 + c * 32 + ig * 8 + 4);
        c1[0] = fmaf(vv, w0.x, c1[0]);
        c1[1] = fmaf(vv, w0.y, c1[1]);
        c1[2] = fmaf(vv, w0.z, c1[2]);
        c1[3] = fmaf(vv, w0.w, c1[3]);
        c1[4] = fmaf(vv, w1.x, c1[4]);
        c1[5] = fmaf(vv, w1.y, c1[5]);
        c1[6] = fmaf(vv, w1.z, c1[6]);
        c1[7] = fmaf(vv, w1.w, c1[7]);
    }
    float pp = 0.f;
#pragma unroll
    for (int u = 0; u < 8; ++u)
        pp = fmaf(fmaxf(c1[u], 0.f), Wc2[ig * 8 + u], pp);
    pp += __shfl_xor(pp, 1);
    pp += __shfl_xor(pp, 2);   // combine the 4 ig groups
    const int g = blockIdx.x * 64 + n2;
    if (ig == 0 && g < N_NODES) out[g] = pp + bc2[0];
}

extern "C" void kernel_launch(void* const* d_in, const int* in_sizes, int n_in,
                              void* d_out, int out_size, void* d_ws, size_t ws_size,
                              hipStream_t stream) {
    const float* x   = (const float*)d_in[0];
    const int*   ei  = (const int*)d_in[1];
    const float* Wl0 = (const float*)d_in[2];
    const float* b0  = (const float*)d_in[3];
    const float* Wr0 = (const float*)d_in[4];
    const float* Wl1 = (const float*)d_in[5];
    const float* b1  = (const float*)d_in[6];
    const float* Wr1 = (const float*)d_in[7];
    const float* Wc1 = (const float*)d_in[8];
    const float* bc1 = (const float*)d_in[9];
    const float* Wc2 = (const float*)d_in[10];
    const float* bc2 = (const float*)d_in[11];
    float* out = (float*)d_out;

    // ws layout (float offsets), liveness-packed (R9-proven):
    float* W = (float*)d_ws;
    int*            part   = (int*)W;                         // dead after scatterB
    int*            btot   = (int*)(W + 200064);
    int*            bstart = (int*)(W + 201632);
    unsigned*       bentry = (unsigned*)(W + 1600000);        // dead after agg0s
    unsigned short* mean0b = (unsigned short*)W;              // dead after transform0
    float*          mean1f = W;                               // written by agg1
    int*            sorted_src = (int*)(W + 3200000);
    int*            off    = (int*)(W + 4800000);
    unsigned short* hb     = (unsigned short*)(W + 4850016);  // N*64 bf16

    const int T = 256;
    histB_kernel<<<NB_BLD, T, 0, stream>>>(ei, part);
    scanA_kernel<<<NBUCK, NB_BLD, 0, stream>>>(part, btot);
    scanB_kernel<<<1, 1024, 0, stream>>>(btot, bstart);
    scatterB_kernel<<<NB_BLD, T, 0, stream>>>(ei, part, bstart, bentry);

    agg0s_kernel<<<NBUCK, T, 0, stream>>>(x, bentry, bstart, sorted_src, off, mean0b);
    transform0_kernel<<<NTB2, T, 0, stream>>>(x, mean0b, Wl0, Wr0, b0, hb);
    const int ngrid = (N_NODES + 3) / 4;
    agg1_kernel<<<ngrid, T, 0, stream>>>(hb, off, sorted_src, mean1f);
    transform1_kernel<<<NTB2, T, 0, stream>>>(hb, mean1f, Wl1, Wr1, b1,
                                              Wc1, bc1, Wc2, bc2, out);
}